// Round 4
// baseline (261.811 us; speedup 1.0000x reference)
//
#include <hip/hip_runtime.h>
#include <hip/hip_bf16.h>
#include <stdint.h>

#define DEVFN __device__ __forceinline__

typedef __attribute__((ext_vector_type(8))) short short8;
typedef __attribute__((ext_vector_type(4))) float f32x4;
typedef __attribute__((ext_vector_type(16))) float f32x16;

constexpr int S_LEN = 2048;   // sequence length
constexpr int HDIM  = 2048;   // hidden H (= K of GEMMs)
constexpr int NHEAD = 16;
constexpr int HD    = 128;    // head dim

DEVFN unsigned short f2bf(float f){
  union { float f; unsigned u; } x; x.f = f;
  unsigned r = x.u + 0x7fffu + ((x.u >> 16) & 1u);
  return (unsigned short)(r >> 16);
}

typedef const __attribute__((address_space(1))) void* gas1_ptr;
typedef __attribute__((address_space(3))) void* las3_ptr;

DEVFN void gl_lds16(const void* g, void* l){
  __builtin_amdgcn_global_load_lds((gas1_ptr)g, (las3_ptr)l, 16, 0, 0);
}

DEVFN f32x4 mfma16(short8 a, short8 b, f32x4 c){
  return __builtin_amdgcn_mfma_f32_16x16x32_bf16(a, b, c, 0, 0, 0);
}

DEVFN f32x16 mfma32(short8 a, short8 b, f32x16 c){
  return __builtin_amdgcn_mfma_f32_32x32x16_bf16(a, b, c, 0, 0, 0);
}

DEVFN unsigned cvtpk_bf16(float lo, float hi){
  unsigned w;
  asm("v_cvt_pk_bf16_f32 %0, %1, %2" : "=v"(w) : "v"(lo), "v"(hi));
  return w;
}

// ---------------- small prep kernels ----------------

__global__ void cast_x_kernel(const float* __restrict__ in, unsigned short* __restrict__ out){
  int i = (blockIdx.x * 256 + threadIdx.x) * 4;
  float4 v = *(const float4*)(in + i);
  ushort4 o;
  o.x = f2bf(v.x); o.y = f2bf(v.y); o.z = f2bf(v.z); o.w = f2bf(v.w);
  *(ushort4*)(out + i) = o;
}

// f32 [K][N] -> bf16 [N][K] for all 4 weights in one launch (z = which weight).
// Outputs are contiguous: Wt (3 x 2048x2048) then Wot (2048x2048).
__global__ void transpose_cast_w4(const float* __restrict__ w0, const float* __restrict__ w1,
                                  const float* __restrict__ w2, const float* __restrict__ w3,
                                  unsigned short* __restrict__ out){
  __shared__ float tile[32][33];
  int tx = threadIdx.x, ty = threadIdx.y;
  int kb = blockIdx.x * 32, nb = blockIdx.y * 32, z = blockIdx.z;
  const float* in = (z == 0) ? w0 : (z == 1) ? w1 : (z == 2) ? w2 : w3;
  unsigned short* op = out + (size_t)z * HDIM * HDIM;
  #pragma unroll
  for (int i = 0; i < 4; i++)
    tile[ty + i*8][tx] = in[(size_t)(kb + ty + i*8) * HDIM + nb + tx];
  __syncthreads();
  #pragma unroll
  for (int i = 0; i < 4; i++)
    op[(size_t)(nb + ty + i*8) * HDIM + kb + tx] = f2bf(tile[tx][ty + i*8]);
}

// bf16 (b,h,s,d) -> (b,h,d,s)
__global__ void transpose_v_kernel(const unsigned short* __restrict__ in,
                                   unsigned short* __restrict__ out){
  __shared__ unsigned short tile[32][34];
  int tx = threadIdx.x, ty = threadIdx.y;
  int sb = blockIdx.x * 32, db = blockIdx.y * 32, bh = blockIdx.z;
  const unsigned short* ip = in + (size_t)bh * S_LEN * HD;
  unsigned short* op = out + (size_t)bh * S_LEN * HD;
  #pragma unroll
  for (int i = 0; i < 4; i++)
    tile[ty + i*8][tx] = ip[(size_t)(sb + ty + i*8) * HD + db + tx];
  __syncthreads();
  #pragma unroll
  for (int i = 0; i < 4; i++)
    op[(size_t)(db + ty + i*8) * S_LEN + sb + tx] = tile[tx][ty + i*8];
}

// ------- GEMM core: A[M][K] x Bt[N][K] -> acc, 256x128 tile, 3-stage pipeline -------
// 512 threads = 8 waves (4 row x 2 col), per-wave 64x64 (4x4 frags of 16x16).
// LDS: 3 buffers x (A 256x64 = 32KB, B 128x64 = 16KB) = 144 KB.
// Per K-tile kt: vmcnt(6) [only K_{kt+1}'s 6 loads may remain -> K_kt landed],
// barrier [all waves done reading buf (kt+2)%3 last iter], stage K_{kt+2} there,
// then ds_read + 32 MFMA. Counted vmcnt (T4): never drain to 0 in the loop.
DEVFN void gemm_core3(const unsigned short* __restrict__ A,
                      const unsigned short* __restrict__ Bt,
                      int K, int m0, int n0, char* ls, f32x4 (&acc)[4][4]){
  const int tid = threadIdx.x;
  const int wid = tid >> 6, lane = tid & 63;
  const int wr = wid >> 1, wc = wid & 1;
  const int l15 = lane & 15, lg = lane >> 4;
  const int nt = K >> 6;

  auto stage = [&](int buf, int kt){
    const char* Ab = (const char*)A + (size_t)kt * 128;   // + k0*2 bytes
    const char* Bb = (const char*)Bt + (size_t)kt * 128;
    char* lb = ls + buf * 49152;
    #pragma unroll
    for (int i = 0; i < 4; i++){     // A: 256 rows x 128 B
      int o = (tid + i*512) * 16;
      int row = o >> 7;
      int col = (o & 127) ^ ((row & 7) << 4);
      gl_lds16(Ab + (size_t)(m0 + row) * (K*2) + col, lb + o);
    }
    #pragma unroll
    for (int i = 4; i < 6; i++){     // B: 128 rows x 128 B
      int o = (tid + i*512) * 16;
      int ob = o - 32768;
      int row = ob >> 7;
      int col = (ob & 127) ^ ((row & 7) << 4);
      gl_lds16(Bb + (size_t)(n0 + row) * (K*2) + col, lb + o);
    }
  };

  stage(0, 0);
  stage(1, 1);
  #pragma unroll 1
  for (int kt = 0; kt < nt; kt++){
    if (kt + 1 < nt) asm volatile("s_waitcnt vmcnt(6)" ::: "memory");
    else             asm volatile("s_waitcnt vmcnt(0)" ::: "memory");
    __builtin_amdgcn_s_barrier();
    if (kt + 2 < nt) stage((kt + 2) % 3, kt + 2);

    const char* lb = ls + (kt % 3) * 49152;
    #pragma unroll
    for (int kk = 0; kk < 2; kk++){
      short8 af[4], bfr[4];
      #pragma unroll
      for (int i = 0; i < 4; i++){
        int ra = wr*64 + i*16 + l15;
        af[i]  = *(const short8*)(lb + ra*128 + ((kk*64 + lg*16) ^ ((ra & 7) << 4)));
        int rb = wc*64 + i*16 + l15;
        bfr[i] = *(const short8*)(lb + 32768 + rb*128 + ((kk*64 + lg*16) ^ ((rb & 7) << 4)));
      }
      #pragma unroll
      for (int i = 0; i < 4; i++)
        #pragma unroll
        for (int j = 0; j < 4; j++)
          acc[i][j] = mfma16(af[i], bfr[j], acc[i][j]);
    }
  }
}

// QKV projection: xb[4096][2048] x Wt[6144][2048] -> scatter bf16 to Q/K/V (b,h,s,d)
// Q pre-scaled by 1/sqrt(HD)*log2(e). Grid: 768 linear blocks, XCD-swizzled.
__global__ __launch_bounds__(512, 2)
void gemm_qkv(const unsigned short* __restrict__ xb, const unsigned short* __restrict__ Wt,
              unsigned short* __restrict__ Qb, unsigned short* __restrict__ Kb,
              unsigned short* __restrict__ Vb){
  __shared__ __align__(16) char ls[147456];
  f32x4 acc[4][4];
  const f32x4 z4 = {0.f, 0.f, 0.f, 0.f};
  #pragma unroll
  for (int i = 0; i < 4; i++)
    #pragma unroll
    for (int j = 0; j < 4; j++) acc[i][j] = z4;

  // bijective XCD swizzle (768 % 8 == 0): chunk of 96 per XCD, by-fast within chunk
  int swz = (blockIdx.x & 7) * 96 + (blockIdx.x >> 3);
  int m0 = (swz / 48) * 256;
  int n0 = (swz % 48) * 128;

  gemm_core3(xb, Wt, HDIM, m0, n0, ls, acc);

  const float qscale = 0.08838834764831845f * 1.4426950408889634f;
  const int tid = threadIdx.x, wid = tid >> 6, lane = tid & 63;
  const int wr = wid >> 1, wc = wid & 1, l15 = lane & 15, lg = lane >> 4;
  #pragma unroll
  for (int j = 0; j < 4; j++){
    int n = n0 + wc*64 + j*16 + l15;
    int sel = n >> 11, hh = (n >> 7) & 15, d = n & 127;
    unsigned short* base = (sel == 0) ? Qb : ((sel == 1) ? Kb : Vb);
    float sc = (sel == 0) ? qscale : 1.0f;
    #pragma unroll
    for (int i = 0; i < 4; i++){
      #pragma unroll
      for (int r = 0; r < 4; r++){
        int m = m0 + wr*64 + i*16 + lg*4 + r;
        int bb = m >> 11, ss = m & 2047;
        base[(((size_t)bb * NHEAD + hh) * S_LEN + ss) * HD + d] = f2bf(acc[i][j][r] * sc);
      }
    }
  }
}

// Output projection: Ob[4096][2048] x Wot[2048][2048] -> out f32 [4096][2048]
__global__ __launch_bounds__(512, 2)
void gemm_out(const unsigned short* __restrict__ Ob, const unsigned short* __restrict__ Wot,
              float* __restrict__ out){
  __shared__ __align__(16) char ls[147456];
  f32x4 acc[4][4];
  const f32x4 z4 = {0.f, 0.f, 0.f, 0.f};
  #pragma unroll
  for (int i = 0; i < 4; i++)
    #pragma unroll
    for (int j = 0; j < 4; j++) acc[i][j] = z4;

  // bijective XCD swizzle (256 % 8 == 0): chunk of 32 per XCD
  int swz = (blockIdx.x & 7) * 32 + (blockIdx.x >> 3);
  int m0 = (swz / 16) * 256;
  int n0 = (swz % 16) * 128;

  gemm_core3(Ob, Wot, HDIM, m0, n0, ls, acc);

  const int tid = threadIdx.x, wid = tid >> 6, lane = tid & 63;
  const int wr = wid >> 1, wc = wid & 1, l15 = lane & 15, lg = lane >> 4;
  #pragma unroll
  for (int i = 0; i < 4; i++){
    #pragma unroll
    for (int r = 0; r < 4; r++){
      int m = m0 + wr*64 + i*16 + lg*4 + r;
      #pragma unroll
      for (int j = 0; j < 4; j++){
        int n = n0 + wc*64 + j*16 + l15;
        out[(size_t)m * HDIM + n] = acc[i][j][r];
      }
    }
  }
}

// ---------------- causal flash attention: swapped-operand 32x32 MFMA ----------------
// grid = 512 linear blocks, 256 threads (4 waves x QBLK=32 rows).
// bh = L&31 (XCD locality: same head -> same L2), qt = z<8 ? z : 23-z (pair balance).
// QK^T: mfma32(A=K, B=Q) -> P[q=lane&31][k in regs]; PV: mfma32(A=V^T, B=P) ->
// O[q=lane&31][d in regs]. Softmax fully in-register (1 shfl_xor(32) per tile).
__global__ __launch_bounds__(256, 2)
void attn_kernel(const unsigned short* __restrict__ Q,
                 const unsigned short* __restrict__ Kg,
                 const unsigned short* __restrict__ Vt,
                 unsigned short* __restrict__ Ob){
  __shared__ __align__(16) unsigned short Kl[2][64*128];   // 2 x 16 KB, rows 256B, xor (row&15)<<4
  __shared__ __align__(16) unsigned short Vl[2][128*64];   // 2 x 16 KB, rows 128B, xor (row&7)<<4

  const int t = threadIdx.x;
  const int wid = t >> 6, lane = t & 63;
  const int l31 = lane & 31, hi = lane >> 5;
  const int L = blockIdx.x;
  const int bh = L & 31;
  const int z = L >> 5;
  const int qt = (z < 8) ? z : 23 - z;
  const int b = bh >> 4, h = bh & 15;
  const unsigned short* Qp = Q  + (size_t)bh * S_LEN * HD;
  const unsigned short* Kp = Kg + (size_t)bh * S_LEN * HD;
  const unsigned short* Vp = Vt + (size_t)bh * S_LEN * HD; // (d, s)
  const int q0 = qt * 128;
  const int wrow0 = q0 + wid * 32;
  const int qrow = wrow0 + l31;
  const int nt = 2 * qt + 2;

  auto stage = [&](int buf, int k0){
    #pragma unroll
    for (int i = 0; i < 4; i++){ // K tile: 64 rows x 256 B
      int o = (t + i*256) * 16;
      int row = o >> 8;
      int col = (o & 255) ^ ((row & 15) << 4);
      gl_lds16((const char*)(Kp + (size_t)(k0 + row) * HD) + col, (char*)&Kl[buf][0] + o);
    }
    #pragma unroll
    for (int i = 0; i < 4; i++){ // V tile: 128 d-rows x 128 B
      int o = (t + i*256) * 16;
      int row = o >> 7;
      int col = (o & 127) ^ ((row & 7) << 4);
      gl_lds16((const char*)(Vp + (size_t)row * S_LEN + k0) + col, (char*)&Vl[buf][0] + o);
    }
  };

  // Q fragments: B[col=qrow][k=d], k = hi*8 + j within each 16-chunk
  short8 qf[8];
  #pragma unroll
  for (int dk = 0; dk < 8; dk++)
    qf[dk] = *(const short8*)(Qp + (size_t)qrow * HD + dk*16 + hi*8);

  f32x16 oacc[4];
  #pragma unroll
  for (int db = 0; db < 4; db++)
    #pragma unroll
    for (int r = 0; r < 16; r++) oacc[db][r] = 0.f;
  float mrun = -1e30f, lsum = 0.f;

  stage(0, 0);
  asm volatile("s_waitcnt vmcnt(0)" ::: "memory");
  __builtin_amdgcn_s_barrier();

  int cur = 0;
  #pragma unroll 1
  for (int tdx = 0; tdx < nt; tdx++){
    if (tdx + 1 < nt) stage(cur ^ 1, (tdx + 1) * 64);
    const int k0 = tdx * 64;

    if (k0 <= wrow0 + 31){   // wave-uniform causal skip
      const char* Kb_ = (const char*)&Kl[cur][0];
      const char* Vb_ = (const char*)&Vl[cur][0];

      // ---- QK^T: S^T = K x Q^T -> sacc[cb][reg]: q = l31, kcol = cb*32 + pat(reg,hi)
      f32x16 sacc[2];
      #pragma unroll
      for (int cb = 0; cb < 2; cb++)
        #pragma unroll
        for (int r = 0; r < 16; r++) sacc[cb][r] = 0.f;
      __builtin_amdgcn_s_setprio(1);
      #pragma unroll
      for (int dk = 0; dk < 8; dk++){
        #pragma unroll
        for (int cb = 0; cb < 2; cb++){
          int kr = cb*32 + l31;
          short8 af = *(const short8*)(Kb_ + kr*256 + ((dk*32 + hi*16) ^ ((kr & 15) << 4)));
          sacc[cb] = mfma32(af, qf[dk], sacc[cb]);
        }
      }
      __builtin_amdgcn_s_setprio(0);

      // ---- causal mask (diagonal tiles only) ----
      if (k0 + 64 > wrow0){
        #pragma unroll
        for (int cb = 0; cb < 2; cb++)
          #pragma unroll
          for (int r = 0; r < 16; r++){
            int kcol = k0 + cb*32 + (r & 3) + 8*(r >> 2) + 4*hi;
            if (kcol > qrow) sacc[cb][r] = -1e30f;
          }
      }

      // ---- online softmax, in-register (defer-max, THR=8) ----
      float mv[8];
      #pragma unroll
      for (int i = 0; i < 8; i++)
        mv[i] = fmaxf(fmaxf(sacc[0][i], sacc[0][i+8]), fmaxf(sacc[1][i], sacc[1][i+8]));
      #pragma unroll
      for (int s = 4; s > 0; s >>= 1)
        #pragma unroll
        for (int i = 0; i < 4; i++)
          if (i < s) mv[i] = fmaxf(mv[i], mv[i+s]);
      float mx = fmaxf(mv[0], __shfl_xor(mv[0], 32, 64));
      if (!__all(mx <= mrun + 8.f)){
        float mnew = fmaxf(mrun, mx);
        float alpha = exp2f(mrun - mnew);
        mrun = mnew;
        lsum *= alpha;
        #pragma unroll
        for (int db = 0; db < 4; db++)
          #pragma unroll
          for (int r = 0; r < 16; r++) oacc[db][r] *= alpha;
      }
      float ls = 0.f;
      #pragma unroll
      for (int cb = 0; cb < 2; cb++)
        #pragma unroll
        for (int r = 0; r < 16; r++){
          float p = exp2f(sacc[cb][r] - mrun);
          sacc[cb][r] = p;
          ls += p;
        }
      lsum += ls;  // per-lane partial; halves combined in epilogue

      // ---- build PV B-fragments: pa[ks][j] = P[q][k=16ks+8hi+j] (bf16) ----
      short8 pa[4];
      #pragma unroll
      for (int ks = 0; ks < 4; ks++){
        int cb = ks >> 1, bs = (ks & 1) * 8;
        unsigned A1 = cvtpk_bf16(sacc[cb][bs+4], sacc[cb][bs+5]);
        unsigned B1 = cvtpk_bf16(sacc[cb][bs+0], sacc[cb][bs+1]);
        unsigned A2 = cvtpk_bf16(sacc[cb][bs+6], sacc[cb][bs+7]);
        unsigned B2 = cvtpk_bf16(sacc[cb][bs+2], sacc[cb][bs+3]);
        unsigned oA1 = __shfl_xor(A1, 32, 64), oB1 = __shfl_xor(B1, 32, 64);
        unsigned oA2 = __shfl_xor(A2, 32, 64), oB2 = __shfl_xor(B2, 32, 64);
        union { unsigned u[4]; short8 v; } pk;
        pk.u[0] = hi ? oA1 : B1;   // (j0,j1)
        pk.u[1] = hi ? oA2 : B2;   // (j2,j3)
        pk.u[2] = hi ? A1 : oB1;   // (j4,j5)
        pk.u[3] = hi ? A2 : oB2;   // (j6,j7)
        pa[ks] = pk.v;
      }

      // ---- PV: O^T += V^T x P^T -> oacc[db][reg]: q = l31, d = db*32 + pat(reg,hi)
      __builtin_amdgcn_s_setprio(1);
      #pragma unroll
      for (int ks = 0; ks < 4; ks++){
        #pragma unroll
        for (int db = 0; db < 4; db++){
          int vr = db*32 + l31;
          short8 vf = *(const short8*)(Vb_ + vr*128 + ((ks*32 + hi*16) ^ ((vr & 7) << 4)));
          oacc[db] = mfma32(vf, pa[ks], oacc[db]);
        }
      }
      __builtin_amdgcn_s_setprio(0);
    }

    asm volatile("s_waitcnt vmcnt(0)" ::: "memory");
    __builtin_amdgcn_s_barrier();
    cur ^= 1;
  }

  // ---- epilogue: combine halves, normalize, pack, LDS transpose, coalesced store
  float lt = lsum + __shfl_xor(lsum, 32, 64);
  float inv = 1.f / lt;
  #pragma unroll
  for (int db = 0; db < 4; db++)
    #pragma unroll
    for (int r = 0; r < 16; r++) oacc[db][r] *= inv;

  char* reg_lds = (char*)&Kl[0][0] + wid * 8192;  // per-wave 32 q x 128 d x 2B
  #pragma unroll
  for (int ms = 0; ms < 8; ms++){
    int db = ms >> 1, bs = (ms & 1) * 8;
    unsigned A1 = cvtpk_bf16(oacc[db][bs+4], oacc[db][bs+5]);
    unsigned B1 = cvtpk_bf16(oacc[db][bs+0], oacc[db][bs+1]);
    unsigned A2 = cvtpk_bf16(oacc[db][bs+6], oacc[db][bs+7]);
    unsigned B2 = cvtpk_bf16(oacc[db][bs+2], oacc[db][bs+3]);
    unsigned oA1 = __shfl_xor(A1, 32, 64), oB1 = __shfl_xor(B1, 32, 64);
    unsigned oA2 = __shfl_xor(A2, 32, 64), oB2 = __shfl_xor(B2, 32, 64);
    union { unsigned u[4]; short8 v; } pk;
    pk.u[0] = hi ? oA1 : B1;
    pk.u[1] = hi ? oA2 : B2;
    pk.u[2] = hi ? A1 : oB1;
    pk.u[3] = hi ? A2 : oB2;
    int byteo = l31*256 + ((ms*32 + hi*16) ^ ((l31 & 7) << 4));
    *(short8*)(reg_lds + byteo) = pk.v;
  }
  #pragma unroll
  for (int i = 0; i < 8; i++){
    int r = (lane >> 4) + i*4;
    int c = lane & 15;
    short8 v = *(const short8*)(reg_lds + r*256 + ((c*16) ^ ((r & 7) << 4)));
    *(short8*)(Ob + ((size_t)(b * S_LEN + wrow0 + r)) * 2048 + h*128 + c*8) = v;
  }
}

// ---------------- launcher ----------------
// ws layout (bytes):
//   [0,          16777216)  xb   (4096x2048 bf16)      -- reused as Ob after QKV GEMM
//   [16777216,   41943040)  Wt   (6144x2048 bf16)      -- reused as Vt after QKV GEMM
//   [41943040,   50331648)  Wot  (2048x2048 bf16)      -- contiguous after Wt
//   [50331648,   67108864)  Qb   (b,h,s,d bf16)
//   [67108864,   83886080)  Kb
//   [83886080,  100663296)  Vb
extern "C" void kernel_launch(void* const* d_in, const int* in_sizes, int n_in,
                              void* d_out, int out_size, void* d_ws, size_t ws_size,
                              hipStream_t stream){
  const float* x  = (const float*)d_in[0];
  // d_in[1] = mask (causal tril; hardcoded in attn_kernel)
  const float* Wq = (const float*)d_in[2];
  const float* Wk = (const float*)d_in[3];
  const float* Wv = (const float*)d_in[4];
  const float* Wo = (const float*)d_in[5];

  char* ws = (char*)d_ws;
  unsigned short* xb  = (unsigned short*)(ws);
  unsigned short* Wt  = (unsigned short*)(ws + 16777216);
  unsigned short* Wot = (unsigned short*)(ws + 41943040);
  unsigned short* Qb  = (unsigned short*)(ws + 50331648);
  unsigned short* Kb  = (unsigned short*)(ws + 67108864);
  unsigned short* Vb  = (unsigned short*)(ws + 83886080);
  unsigned short* Vt  = Wt;  // alias: Wt dead after gemm_qkv
  unsigned short* Ob  = xb;  // alias: xb dead after gemm_qkv

  dim3 tb(32, 8);
  cast_x_kernel<<<8192, 256, 0, stream>>>(x, xb);
  transpose_cast_w4<<<dim3(64, 64, 4), tb, 0, stream>>>(Wq, Wk, Wv, Wo, Wt);

  gemm_qkv<<<768, 512, 0, stream>>>(xb, Wt, Qb, Kb, Vb);

  transpose_v_kernel<<<dim3(64, 4, 32), tb, 0, stream>>>(Vb, Vt);

  attn_kernel<<<512, 256, 0, stream>>>(Qb, Kb, Vt, Ob);

  gemm_out<<<256, 512, 0, stream>>>(Ob, Wot, (float*)d_out);
}

// Round 5
// 242.663 us; speedup vs baseline: 1.0789x; 1.0789x over previous
//
#include <hip/hip_runtime.h>
#include <hip/hip_bf16.h>
#include <stdint.h>

#define DEVFN __device__ __forceinline__

typedef __attribute__((ext_vector_type(8))) short short8;
typedef __attribute__((ext_vector_type(4))) float f32x4;
typedef __attribute__((ext_vector_type(16))) float f32x16;

constexpr int S_LEN = 2048;   // sequence length
constexpr int HDIM  = 2048;   // hidden H (= K of GEMMs)
constexpr int NHEAD = 16;
constexpr int HD    = 128;    // head dim

DEVFN unsigned short f2bf(float f){
  union { float f; unsigned u; } x; x.f = f;
  unsigned r = x.u + 0x7fffu + ((x.u >> 16) & 1u);
  return (unsigned short)(r >> 16);
}

typedef const __attribute__((address_space(1))) void* gas1_ptr;
typedef __attribute__((address_space(3))) void* las3_ptr;

DEVFN void gl_lds16(const void* g, void* l){
  __builtin_amdgcn_global_load_lds((gas1_ptr)g, (las3_ptr)l, 16, 0, 0);
}

DEVFN f32x4 mfma16(short8 a, short8 b, f32x4 c){
  return __builtin_amdgcn_mfma_f32_16x16x32_bf16(a, b, c, 0, 0, 0);
}

DEVFN f32x16 mfma32(short8 a, short8 b, f32x16 c){
  return __builtin_amdgcn_mfma_f32_32x32x16_bf16(a, b, c, 0, 0, 0);
}

DEVFN unsigned cvtpk_bf16(float lo, float hi){
  unsigned w;
  asm("v_cvt_pk_bf16_f32 %0, %1, %2" : "=v"(w) : "v"(lo), "v"(hi));
  return w;
}

// ---------------- small prep kernels ----------------

__global__ void cast_x_kernel(const float* __restrict__ in, unsigned short* __restrict__ out){
  int i = (blockIdx.x * 256 + threadIdx.x) * 4;
  float4 v = *(const float4*)(in + i);
  ushort4 o;
  o.x = f2bf(v.x); o.y = f2bf(v.y); o.z = f2bf(v.z); o.w = f2bf(v.w);
  *(ushort4*)(out + i) = o;
}

// f32 [K][N] -> bf16 [N][K] for all 4 weights in one launch (z = which weight).
// Outputs contiguous: Wt (3 x 2048x2048) then Wot (2048x2048).
__global__ void transpose_cast_w4(const float* __restrict__ w0, const float* __restrict__ w1,
                                  const float* __restrict__ w2, const float* __restrict__ w3,
                                  unsigned short* __restrict__ out){
  __shared__ float tile[32][33];
  int tx = threadIdx.x, ty = threadIdx.y;
  int kb = blockIdx.x * 32, nb = blockIdx.y * 32, z = blockIdx.z;
  const float* in = (z == 0) ? w0 : (z == 1) ? w1 : (z == 2) ? w2 : w3;
  unsigned short* op = out + (size_t)z * HDIM * HDIM;
  #pragma unroll
  for (int i = 0; i < 4; i++)
    tile[ty + i*8][tx] = in[(size_t)(kb + ty + i*8) * HDIM + nb + tx];
  __syncthreads();
  #pragma unroll
  for (int i = 0; i < 4; i++)
    op[(size_t)(nb + ty + i*8) * HDIM + kb + tx] = f2bf(tile[tx][ty + i*8]);
}

// ---------------- GEMM core: A[M][K] x Bt[N][K] -> acc (128x128 tile) ----------------
// 256 threads = 4 waves (2x2), per-wave 64x64 = 4x4 fragments of 16x16.
// ls: A tile at [0,16384), B tile at [16384,32768). Single-buffered m97 structure.

DEVFN void gemm_core_bt(const unsigned short* __restrict__ A,
                        const unsigned short* __restrict__ Bt,
                        int K, int m0, int n0, char* ls, f32x4 (&acc)[4][4]){
  const int t = threadIdx.x;
  const int wid = t >> 6, lane = t & 63;
  const int wr = wid >> 1, wc = wid & 1;
  const int l15 = lane & 15, lg = lane >> 4;
  char* lsA = ls;
  char* lsB = ls + 16384;

  for (int k0 = 0; k0 < K; k0 += 64){
    __syncthreads();
    #pragma unroll
    for (int i = 0; i < 4; i++){
      int o = (t + i*256) * 16;
      int row = o >> 7;
      int col = (o & 127) ^ ((row & 7) << 4);
      gl_lds16((const char*)A + ((size_t)(m0 + row) * K + k0) * 2 + col, lsA + o);
    }
    #pragma unroll
    for (int i = 0; i < 4; i++){
      int o = (t + i*256) * 16;
      int row = o >> 7;
      int col = (o & 127) ^ ((row & 7) << 4);
      gl_lds16((const char*)Bt + ((size_t)(n0 + row) * K + k0) * 2 + col, lsB + o);
    }
    __syncthreads();
    #pragma unroll
    for (int kk = 0; kk < 2; kk++){
      short8 af[4], bfr[4];
      #pragma unroll
      for (int i = 0; i < 4; i++){
        int ra = wr*64 + i*16 + l15;
        af[i]  = *(const short8*)(lsA + ra*128 + ((kk*64 + lg*16) ^ ((ra & 7) << 4)));
        int rb = wc*64 + i*16 + l15;
        bfr[i] = *(const short8*)(lsB + rb*128 + ((kk*64 + lg*16) ^ ((rb & 7) << 4)));
      }
      #pragma unroll
      for (int i = 0; i < 4; i++)
        #pragma unroll
        for (int j = 0; j < 4; j++)
          acc[i][j] = mfma16(af[i], bfr[j], acc[i][j]);
    }
  }
}

// QKV projection: xb[4096][2048] x Wt[6144][2048].
// Q (scaled by 1/sqrt(HD)*log2e) and K scatter to (b,h,s,d); V is written
// TRANSPOSED to Vt (b,h,d,s) via an LDS 128x128 transpose (replaces the old
// transpose_v kernel). n-panels are 128-wide and head/QKV boundaries are
// 128-aligned, so each block is uniformly Q, K, or V.
__global__ __launch_bounds__(256, 4)
void gemm_qkv(const unsigned short* __restrict__ xb, const unsigned short* __restrict__ Wt,
              unsigned short* __restrict__ Qb, unsigned short* __restrict__ Kb,
              unsigned short* __restrict__ Vt){
  __shared__ __align__(16) char ls[32768];
  f32x4 acc[4][4];
  const f32x4 z4 = {0.f, 0.f, 0.f, 0.f};
  #pragma unroll
  for (int i = 0; i < 4; i++)
    #pragma unroll
    for (int j = 0; j < 4; j++) acc[i][j] = z4;

  const int m0 = blockIdx.x * 128;
  const int n0 = blockIdx.y * 128;
  gemm_core_bt(xb, Wt, HDIM, m0, n0, ls, acc);

  const float qscale = 0.08838834764831845f * 1.4426950408889634f;
  const int t = threadIdx.x, wid = t >> 6, lane = t & 63;
  const int wr = wid >> 1, wc = wid & 1, l15 = lane & 15, lg = lane >> 4;
  const int bb = m0 >> 11, ss0 = m0 & 2047;

  if (n0 < 4096){
    // ---- Q or K: direct scatter to (b,h,s,d) ----
    unsigned short* base = (n0 < 2048) ? Qb : Kb;
    const float sc = (n0 < 2048) ? qscale : 1.0f;
    #pragma unroll
    for (int j = 0; j < 4; j++){
      int n = n0 + wc*64 + j*16 + l15;
      int hh = (n >> 7) & 15, d = n & 127;
      #pragma unroll
      for (int i = 0; i < 4; i++){
        #pragma unroll
        for (int r = 0; r < 4; r++){
          int ss = ss0 + wr*64 + i*16 + lg*4 + r;
          base[(((size_t)bb * NHEAD + hh) * S_LEN + ss) * HD + d] = f2bf(acc[i][j][r] * sc);
        }
      }
    }
  } else {
    // ---- V: LDS transpose -> coalesced (b,h,d,s) store ----
    const int hh = (n0 - 4096) >> 7;
    __syncthreads();  // all waves done reading the gemm LDS tiles
    // stash transposed: tile[d 128][s_local 128] ush, byte xor (d&7)<<4
    #pragma unroll
    for (int j = 0; j < 4; j++){
      int nn = wc*64 + j*16 + l15;        // d
      int rowb = nn*256 + (((nn & 7) << 4));
      #pragma unroll
      for (int i = 0; i < 4; i++){
        int mmb = (wr*64 + i*16 + lg*4) * 2;   // byte offset of s_local
        unsigned w0 = cvtpk_bf16(acc[i][j][0], acc[i][j][1]);
        unsigned w1 = cvtpk_bf16(acc[i][j][2], acc[i][j][3]);
        *(unsigned*)(ls + nn*256 + ((mmb    ) ^ ((nn & 7) << 4))) = w0;
        *(unsigned*)(ls + nn*256 + ((mmb + 4) ^ ((nn & 7) << 4))) = w1;
      }
      (void)rowb;
    }
    __syncthreads();
    // coalesced store: 8 passes x 256 thr x 16B; 16 threads cover one d-row
    unsigned short* vout = Vt + (((size_t)bb * NHEAD + hh) * HD) * S_LEN;
    #pragma unroll
    for (int p = 0; p < 8; p++){
      int idx = p*256 + t;
      int d = idx >> 4;
      int m8 = (idx & 15) * 8;            // s_local start (shorts)
      short8 v = *(const short8*)(ls + d*256 + ((m8*2) ^ ((d & 7) << 4)));
      *(short8*)(vout + (size_t)d * S_LEN + ss0 + m8) = v;
    }
  }
}

// Output projection: Ob[4096][2048] x Wot[2048][2048] -> out f32 [4096][2048]
__global__ __launch_bounds__(256, 4)
void gemm_out(const unsigned short* __restrict__ Ob, const unsigned short* __restrict__ Wot,
              float* __restrict__ out){
  __shared__ __align__(16) char ls[32768];
  f32x4 acc[4][4];
  const f32x4 z4 = {0.f, 0.f, 0.f, 0.f};
  #pragma unroll
  for (int i = 0; i < 4; i++)
    #pragma unroll
    for (int j = 0; j < 4; j++) acc[i][j] = z4;

  const int m0 = blockIdx.x * 128;
  const int n0 = blockIdx.y * 128;
  gemm_core_bt(Ob, Wot, HDIM, m0, n0, ls, acc);

  const int t = threadIdx.x, wid = t >> 6, lane = t & 63;
  const int wr = wid >> 1, wc = wid & 1, l15 = lane & 15, lg = lane >> 4;
  #pragma unroll
  for (int i = 0; i < 4; i++){
    #pragma unroll
    for (int r = 0; r < 4; r++){
      int m = m0 + wr*64 + i*16 + lg*4 + r;
      #pragma unroll
      for (int j = 0; j < 4; j++){
        int n = n0 + wc*64 + j*16 + l15;
        out[(size_t)m * HDIM + n] = acc[i][j][r];
      }
    }
  }
}

// ---------------- causal flash attention: swapped-operand 32x32 MFMA ----------------
// grid = 512 linear blocks, 256 threads (4 waves x QBLK=32 rows).
// bh = L&31 (XCD locality), qt = z<8 ? z : 23-z (pair balance).
__global__ __launch_bounds__(256, 2)
void attn_kernel(const unsigned short* __restrict__ Q,
                 const unsigned short* __restrict__ Kg,
                 const unsigned short* __restrict__ Vt,
                 unsigned short* __restrict__ Ob){
  __shared__ __align__(16) unsigned short Kl[2][64*128];   // 2 x 16 KB, rows 256B, xor (row&15)<<4
  __shared__ __align__(16) unsigned short Vl[2][128*64];   // 2 x 16 KB, rows 128B, xor (row&7)<<4

  const int t = threadIdx.x;
  const int wid = t >> 6, lane = t & 63;
  const int l31 = lane & 31, hi = lane >> 5;
  const int L = blockIdx.x;
  const int bh = L & 31;
  const int z = L >> 5;
  const int qt = (z < 8) ? z : 23 - z;
  const int b = bh >> 4, h = bh & 15;
  const unsigned short* Qp = Q  + (size_t)bh * S_LEN * HD;
  const unsigned short* Kp = Kg + (size_t)bh * S_LEN * HD;
  const unsigned short* Vp = Vt + (size_t)bh * S_LEN * HD; // (d, s)
  const int q0 = qt * 128;
  const int wrow0 = q0 + wid * 32;
  const int qrow = wrow0 + l31;
  const int nt = 2 * qt + 2;

  auto stage = [&](int buf, int k0){
    #pragma unroll
    for (int i = 0; i < 4; i++){ // K tile: 64 rows x 256 B
      int o = (t + i*256) * 16;
      int row = o >> 8;
      int col = (o & 255) ^ ((row & 15) << 4);
      gl_lds16((const char*)(Kp + (size_t)(k0 + row) * HD) + col, (char*)&Kl[buf][0] + o);
    }
    #pragma unroll
    for (int i = 0; i < 4; i++){ // V tile: 128 d-rows x 128 B
      int o = (t + i*256) * 16;
      int row = o >> 7;
      int col = (o & 127) ^ ((row & 7) << 4);
      gl_lds16((const char*)(Vp + (size_t)row * S_LEN + k0) + col, (char*)&Vl[buf][0] + o);
    }
  };

  // Q fragments: B[col=qrow][k=d], k = hi*8 + j within each 16-chunk
  short8 qf[8];
  #pragma unroll
  for (int dk = 0; dk < 8; dk++)
    qf[dk] = *(const short8*)(Qp + (size_t)qrow * HD + dk*16 + hi*8);

  f32x16 oacc[4];
  #pragma unroll
  for (int db = 0; db < 4; db++)
    #pragma unroll
    for (int r = 0; r < 16; r++) oacc[db][r] = 0.f;
  float mrun = -1e30f, lsum = 0.f;

  stage(0, 0);
  asm volatile("s_waitcnt vmcnt(0)" ::: "memory");
  __builtin_amdgcn_s_barrier();

  int cur = 0;
  #pragma unroll 1
  for (int tdx = 0; tdx < nt; tdx++){
    if (tdx + 1 < nt) stage(cur ^ 1, (tdx + 1) * 64);
    const int k0 = tdx * 64;

    if (k0 <= wrow0 + 31){   // wave-uniform causal skip
      const char* Kb_ = (const char*)&Kl[cur][0];
      const char* Vb_ = (const char*)&Vl[cur][0];

      // ---- QK^T: S^T = K x Q^T -> sacc[cb][reg]: q = l31, kcol = cb*32 + pat(reg,hi)
      f32x16 sacc[2];
      #pragma unroll
      for (int cb = 0; cb < 2; cb++)
        #pragma unroll
        for (int r = 0; r < 16; r++) sacc[cb][r] = 0.f;
      __builtin_amdgcn_s_setprio(1);
      #pragma unroll
      for (int dk = 0; dk < 8; dk++){
        #pragma unroll
        for (int cb = 0; cb < 2; cb++){
          int kr = cb*32 + l31;
          short8 af = *(const short8*)(Kb_ + kr*256 + ((dk*32 + hi*16) ^ ((kr & 15) << 4)));
          sacc[cb] = mfma32(af, qf[dk], sacc[cb]);
        }
      }
      __builtin_amdgcn_s_setprio(0);

      // ---- causal mask (diagonal tiles only) ----
      if (k0 + 64 > wrow0){
        #pragma unroll
        for (int cb = 0; cb < 2; cb++)
          #pragma unroll
          for (int r = 0; r < 16; r++){
            int kcol = k0 + cb*32 + (r & 3) + 8*(r >> 2) + 4*hi;
            if (kcol > qrow) sacc[cb][r] = -1e30f;
          }
      }

      // ---- online softmax, in-register (defer-max, THR=8) ----
      float mv[8];
      #pragma unroll
      for (int i = 0; i < 8; i++)
        mv[i] = fmaxf(fmaxf(sacc[0][i], sacc[0][i+8]), fmaxf(sacc[1][i], sacc[1][i+8]));
      #pragma unroll
      for (int s = 4; s > 0; s >>= 1)
        #pragma unroll
        for (int i = 0; i < 4; i++)
          if (i < s) mv[i] = fmaxf(mv[i], mv[i+s]);
      float mx = fmaxf(mv[0], __shfl_xor(mv[0], 32, 64));
      if (!__all(mx <= mrun + 8.f)){
        float mnew = fmaxf(mrun, mx);
        float alpha = exp2f(mrun - mnew);
        mrun = mnew;
        lsum *= alpha;
        #pragma unroll
        for (int db = 0; db < 4; db++)
          #pragma unroll
          for (int r = 0; r < 16; r++) oacc[db][r] *= alpha;
      }
      float ls = 0.f;
      #pragma unroll
      for (int cb = 0; cb < 2; cb++)
        #pragma unroll
        for (int r = 0; r < 16; r++){
          float p = exp2f(sacc[cb][r] - mrun);
          sacc[cb][r] = p;
          ls += p;
        }
      lsum += ls;  // per-lane partial; halves combined in epilogue

      // ---- build PV B-fragments: pa[ks][j] = P[q][k=16ks+8hi+j] (bf16) ----
      short8 pa[4];
      #pragma unroll
      for (int ks = 0; ks < 4; ks++){
        int cb = ks >> 1, bs = (ks & 1) * 8;
        unsigned A1 = cvtpk_bf16(sacc[cb][bs+4], sacc[cb][bs+5]);
        unsigned B1 = cvtpk_bf16(sacc[cb][bs+0], sacc[cb][bs+1]);
        unsigned A2 = cvtpk_bf16(sacc[cb][bs+6], sacc[cb][bs+7]);
        unsigned B2 = cvtpk_bf16(sacc[cb][bs+2], sacc[cb][bs+3]);
        unsigned oA1 = __shfl_xor(A1, 32, 64), oB1 = __shfl_xor(B1, 32, 64);
        unsigned oA2 = __shfl_xor(A2, 32, 64), oB2 = __shfl_xor(B2, 32, 64);
        union { unsigned u[4]; short8 v; } pk;
        pk.u[0] = hi ? oA1 : B1;   // (j0,j1)
        pk.u[1] = hi ? oA2 : B2;   // (j2,j3)
        pk.u[2] = hi ? A1 : oB1;   // (j4,j5)
        pk.u[3] = hi ? A2 : oB2;   // (j6,j7)
        pa[ks] = pk.v;
      }

      // ---- PV: O^T += V^T x P^T -> oacc[db][reg]: q = l31, d = db*32 + pat(reg,hi)
      __builtin_amdgcn_s_setprio(1);
      #pragma unroll
      for (int ks = 0; ks < 4; ks++){
        #pragma unroll
        for (int db = 0; db < 4; db++){
          int vr = db*32 + l31;
          short8 vf = *(const short8*)(Vb_ + vr*128 + ((ks*32 + hi*16) ^ ((vr & 7) << 4)));
          oacc[db] = mfma32(vf, pa[ks], oacc[db]);
        }
      }
      __builtin_amdgcn_s_setprio(0);
    }

    asm volatile("s_waitcnt vmcnt(0)" ::: "memory");
    __builtin_amdgcn_s_barrier();
    cur ^= 1;
  }

  // ---- epilogue: combine halves, normalize, pack, LDS transpose, coalesced store
  float lt = lsum + __shfl_xor(lsum, 32, 64);
  float inv = 1.f / lt;
  #pragma unroll
  for (int db = 0; db < 4; db++)
    #pragma unroll
    for (int r = 0; r < 16; r++) oacc[db][r] *= inv;

  char* reg_lds = (char*)&Kl[0][0] + wid * 8192;  // per-wave 32 q x 128 d x 2B
  #pragma unroll
  for (int ms = 0; ms < 8; ms++){
    int db = ms >> 1, bs = (ms & 1) * 8;
    unsigned A1 = cvtpk_bf16(oacc[db][bs+4], oacc[db][bs+5]);
    unsigned B1 = cvtpk_bf16(oacc[db][bs+0], oacc[db][bs+1]);
    unsigned A2 = cvtpk_bf16(oacc[db][bs+6], oacc[db][bs+7]);
    unsigned B2 = cvtpk_bf16(oacc[db][bs+2], oacc[db][bs+3]);
    unsigned oA1 = __shfl_xor(A1, 32, 64), oB1 = __shfl_xor(B1, 32, 64);
    unsigned oA2 = __shfl_xor(A2, 32, 64), oB2 = __shfl_xor(B2, 32, 64);
    union { unsigned u[4]; short8 v; } pk;
    pk.u[0] = hi ? oA1 : B1;
    pk.u[1] = hi ? oA2 : B2;
    pk.u[2] = hi ? A1 : oB1;
    pk.u[3] = hi ? A2 : oB2;
    int byteo = l31*256 + ((ms*32 + hi*16) ^ ((l31 & 7) << 4));
    *(short8*)(reg_lds + byteo) = pk.v;
  }
  #pragma unroll
  for (int i = 0; i < 8; i++){
    int r = (lane >> 4) + i*4;
    int c = lane & 15;
    short8 v = *(const short8*)(reg_lds + r*256 + ((c*16) ^ ((r & 7) << 4)));
    *(short8*)(Ob + ((size_t)(b * S_LEN + wrow0 + r)) * 2048 + h*128 + c*8) = v;
  }
}

// ---------------- launcher ----------------
// ws layout (bytes):
//   [0,          16777216)  xb   (4096x2048 bf16)      -- reused as Ob after QKV GEMM
//   [16777216,   41943040)  Wt   (6144x2048 bf16)
//   [41943040,   50331648)  Wot  (2048x2048 bf16)      -- contiguous after Wt
//   [50331648,   67108864)  Qb   (b,h,s,d bf16)
//   [67108864,   83886080)  Kb
//   [83886080,  100663296)  Vt   (b,h,d,s bf16, written directly by gemm_qkv)
extern "C" void kernel_launch(void* const* d_in, const int* in_sizes, int n_in,
                              void* d_out, int out_size, void* d_ws, size_t ws_size,
                              hipStream_t stream){
  const float* x  = (const float*)d_in[0];
  // d_in[1] = mask (causal tril; hardcoded in attn_kernel)
  const float* Wq = (const float*)d_in[2];
  const float* Wk = (const float*)d_in[3];
  const float* Wv = (const float*)d_in[4];
  const float* Wo = (const float*)d_in[5];

  char* ws = (char*)d_ws;
  unsigned short* xb  = (unsigned short*)(ws);
  unsigned short* Wt  = (unsigned short*)(ws + 16777216);
  unsigned short* Wot = (unsigned short*)(ws + 41943040);
  unsigned short* Qb  = (unsigned short*)(ws + 50331648);
  unsigned short* Kb  = (unsigned short*)(ws + 67108864);
  unsigned short* Vt  = (unsigned short*)(ws + 83886080);
  unsigned short* Ob  = xb;  // alias: xb dead after gemm_qkv

  dim3 tb(32, 8);
  cast_x_kernel<<<8192, 256, 0, stream>>>(x, xb);
  transpose_cast_w4<<<dim3(64, 64, 4), tb, 0, stream>>>(Wq, Wk, Wv, Wo, Wt);

  gemm_qkv<<<dim3(32, 48), 256, 0, stream>>>(xb, Wt, Qb, Kb, Vt);

  attn_kernel<<<512, 256, 0, stream>>>(Qb, Kb, Vt, Ob);

  gemm_out<<<dim3(32, 16), 256, 0, stream>>>(Ob, Wot, (float*)d_out);
}

// Round 6
// 231.776 us; speedup vs baseline: 1.1296x; 1.0470x over previous
//
#include <hip/hip_runtime.h>
#include <hip/hip_bf16.h>
#include <stdint.h>

#define DEVFN __device__ __forceinline__

typedef __attribute__((ext_vector_type(8))) short short8;
typedef __attribute__((ext_vector_type(4))) float f32x4;
typedef __attribute__((ext_vector_type(16))) float f32x16;

constexpr int S_LEN = 2048;   // sequence length
constexpr int HDIM  = 2048;   // hidden H (= K of GEMMs)
constexpr int NHEAD = 16;
constexpr int HD    = 128;    // head dim

DEVFN unsigned short f2bf(float f){
  union { float f; unsigned u; } x; x.f = f;
  unsigned r = x.u + 0x7fffu + ((x.u >> 16) & 1u);
  return (unsigned short)(r >> 16);
}

typedef const __attribute__((address_space(1))) void* gas1_ptr;
typedef __attribute__((address_space(3))) void* las3_ptr;

DEVFN void gl_lds16(const void* g, void* l){
  __builtin_amdgcn_global_load_lds((gas1_ptr)g, (las3_ptr)l, 16, 0, 0);
}

DEVFN f32x4 mfma16(short8 a, short8 b, f32x4 c){
  return __builtin_amdgcn_mfma_f32_16x16x32_bf16(a, b, c, 0, 0, 0);
}

DEVFN f32x16 mfma32(short8 a, short8 b, f32x16 c){
  return __builtin_amdgcn_mfma_f32_32x32x16_bf16(a, b, c, 0, 0, 0);
}

DEVFN unsigned cvtpk_bf16(float lo, float hi){
  unsigned w;
  asm("v_cvt_pk_bf16_f32 %0, %1, %2" : "=v"(w) : "v"(lo), "v"(hi));
  return w;
}

// ---------------- small prep kernels ----------------

__global__ void cast_x_kernel(const float* __restrict__ in, unsigned short* __restrict__ out){
  int i = (blockIdx.x * 256 + threadIdx.x) * 4;
  float4 v = *(const float4*)(in + i);
  ushort4 o;
  o.x = f2bf(v.x); o.y = f2bf(v.y); o.z = f2bf(v.z); o.w = f2bf(v.w);
  *(ushort4*)(out + i) = o;
}

// f32 [K][N] -> bf16 [N][K] for all 4 weights in one launch (z = which weight).
__global__ void transpose_cast_w4(const float* __restrict__ w0, const float* __restrict__ w1,
                                  const float* __restrict__ w2, const float* __restrict__ w3,
                                  unsigned short* __restrict__ out){
  __shared__ float tile[32][33];
  int tx = threadIdx.x, ty = threadIdx.y;
  int kb = blockIdx.x * 32, nb = blockIdx.y * 32, z = blockIdx.z;
  const float* in = (z == 0) ? w0 : (z == 1) ? w1 : (z == 2) ? w2 : w3;
  unsigned short* op = out + (size_t)z * HDIM * HDIM;
  #pragma unroll
  for (int i = 0; i < 4; i++)
    tile[ty + i*8][tx] = in[(size_t)(kb + ty + i*8) * HDIM + nb + tx];
  __syncthreads();
  #pragma unroll
  for (int i = 0; i < 4; i++)
    op[(size_t)(nb + ty + i*8) * HDIM + kb + tx] = f2bf(tile[tx][ty + i*8]);
}

// ---------------- GEMM core: A[M][K] x Bt[N][K] -> acc (128x128 tile) ----------------
// 256 threads = 4 waves (2x2), per-wave 64x64 = 4x4 fragments of 16x16.

DEVFN void gemm_core_bt(const unsigned short* __restrict__ A,
                        const unsigned short* __restrict__ Bt,
                        int K, int m0, int n0, char* ls, f32x4 (&acc)[4][4]){
  const int t = threadIdx.x;
  const int wid = t >> 6, lane = t & 63;
  const int wr = wid >> 1, wc = wid & 1;
  const int l15 = lane & 15, lg = lane >> 4;
  char* lsA = ls;
  char* lsB = ls + 16384;

  for (int k0 = 0; k0 < K; k0 += 64){
    __syncthreads();
    #pragma unroll
    for (int i = 0; i < 4; i++){
      int o = (t + i*256) * 16;
      int row = o >> 7;
      int col = (o & 127) ^ ((row & 7) << 4);
      gl_lds16((const char*)A + ((size_t)(m0 + row) * K + k0) * 2 + col, lsA + o);
    }
    #pragma unroll
    for (int i = 0; i < 4; i++){
      int o = (t + i*256) * 16;
      int row = o >> 7;
      int col = (o & 127) ^ ((row & 7) << 4);
      gl_lds16((const char*)Bt + ((size_t)(n0 + row) * K + k0) * 2 + col, lsB + o);
    }
    __syncthreads();
    #pragma unroll
    for (int kk = 0; kk < 2; kk++){
      short8 af[4], bfr[4];
      #pragma unroll
      for (int i = 0; i < 4; i++){
        int ra = wr*64 + i*16 + l15;
        af[i]  = *(const short8*)(lsA + ra*128 + ((kk*64 + lg*16) ^ ((ra & 7) << 4)));
        int rb = wc*64 + i*16 + l15;
        bfr[i] = *(const short8*)(lsB + rb*128 + ((kk*64 + lg*16) ^ ((rb & 7) << 4)));
      }
      #pragma unroll
      for (int i = 0; i < 4; i++)
        #pragma unroll
        for (int j = 0; j < 4; j++)
          acc[i][j] = mfma16(af[i], bfr[j], acc[i][j]);
    }
  }
}

// QKV projection: xb[4096][2048] x Wt[6144][2048].
// Q (scaled by 1/sqrt(HD)*log2e) and K scatter to (b,h,s,d); V is written
// TRANSPOSED to Vt (b,h,d,s) via an LDS 128x128 transpose.
__global__ __launch_bounds__(256, 4)
void gemm_qkv(const unsigned short* __restrict__ xb, const unsigned short* __restrict__ Wt,
              unsigned short* __restrict__ Qb, unsigned short* __restrict__ Kb,
              unsigned short* __restrict__ Vt){
  __shared__ __align__(16) char ls[32768];
  f32x4 acc[4][4];
  const f32x4 z4 = {0.f, 0.f, 0.f, 0.f};
  #pragma unroll
  for (int i = 0; i < 4; i++)
    #pragma unroll
    for (int j = 0; j < 4; j++) acc[i][j] = z4;

  const int m0 = blockIdx.x * 128;
  const int n0 = blockIdx.y * 128;
  gemm_core_bt(xb, Wt, HDIM, m0, n0, ls, acc);

  const float qscale = 0.08838834764831845f * 1.4426950408889634f;
  const int t = threadIdx.x, wid = t >> 6, lane = t & 63;
  const int wr = wid >> 1, wc = wid & 1, l15 = lane & 15, lg = lane >> 4;
  const int bb = m0 >> 11, ss0 = m0 & 2047;

  if (n0 < 4096){
    unsigned short* base = (n0 < 2048) ? Qb : Kb;
    const float sc = (n0 < 2048) ? qscale : 1.0f;
    #pragma unroll
    for (int j = 0; j < 4; j++){
      int n = n0 + wc*64 + j*16 + l15;
      int hh = (n >> 7) & 15, d = n & 127;
      #pragma unroll
      for (int i = 0; i < 4; i++){
        #pragma unroll
        for (int r = 0; r < 4; r++){
          int ss = ss0 + wr*64 + i*16 + lg*4 + r;
          base[(((size_t)bb * NHEAD + hh) * S_LEN + ss) * HD + d] = f2bf(acc[i][j][r] * sc);
        }
      }
    }
  } else {
    // V: LDS transpose -> coalesced (b,h,d,s) store
    const int hh = (n0 - 4096) >> 7;
    __syncthreads();
    #pragma unroll
    for (int j = 0; j < 4; j++){
      int nn = wc*64 + j*16 + l15;        // d
      #pragma unroll
      for (int i = 0; i < 4; i++){
        int mmb = (wr*64 + i*16 + lg*4) * 2;
        unsigned w0 = cvtpk_bf16(acc[i][j][0], acc[i][j][1]);
        unsigned w1 = cvtpk_bf16(acc[i][j][2], acc[i][j][3]);
        *(unsigned*)(ls + nn*256 + ((mmb    ) ^ ((nn & 7) << 4))) = w0;
        *(unsigned*)(ls + nn*256 + ((mmb + 4) ^ ((nn & 7) << 4))) = w1;
      }
    }
    __syncthreads();
    unsigned short* vout = Vt + (((size_t)bb * NHEAD + hh) * HD) * S_LEN;
    #pragma unroll
    for (int p = 0; p < 8; p++){
      int idx = p*256 + t;
      int d = idx >> 4;
      int m8 = (idx & 15) * 8;
      short8 v = *(const short8*)(ls + d*256 + ((m8*2) ^ ((d & 7) << 4)));
      *(short8*)(vout + (size_t)d * S_LEN + ss0 + m8) = v;
    }
  }
}

// Output projection: Ob[4096][2048] x Wot[2048][2048] -> out f32 [4096][2048]
__global__ __launch_bounds__(256, 4)
void gemm_out(const unsigned short* __restrict__ Ob, const unsigned short* __restrict__ Wot,
              float* __restrict__ out){
  __shared__ __align__(16) char ls[32768];
  f32x4 acc[4][4];
  const f32x4 z4 = {0.f, 0.f, 0.f, 0.f};
  #pragma unroll
  for (int i = 0; i < 4; i++)
    #pragma unroll
    for (int j = 0; j < 4; j++) acc[i][j] = z4;

  const int m0 = blockIdx.x * 128;
  const int n0 = blockIdx.y * 128;
  gemm_core_bt(Ob, Wot, HDIM, m0, n0, ls, acc);

  const int t = threadIdx.x, wid = t >> 6, lane = t & 63;
  const int wr = wid >> 1, wc = wid & 1, l15 = lane & 15, lg = lane >> 4;
  #pragma unroll
  for (int i = 0; i < 4; i++){
    #pragma unroll
    for (int r = 0; r < 4; r++){
      int m = m0 + wr*64 + i*16 + lg*4 + r;
      #pragma unroll
      for (int j = 0; j < 4; j++){
        int n = n0 + wc*64 + j*16 + l15;
        out[(size_t)m * HDIM + n] = acc[i][j][r];
      }
    }
  }
}

// ---------------- causal flash attention: swapped 32x32 MFMA + lagged-PV pipeline --
// grid = 512 linear blocks, 256 threads (4 waves x QBLK=32 rows).
// bh = L&31 (XCD locality), qt = z<8 ? z : 23-z (pair balance).
// Loop body t: stage(t+1) -> QK(t) -> PV(t-1) [lagged, V 3-buffered] -> SM(t).
// The two MFMA bursts are independent; softmax VALU drops off the MFMA-feed path.
// pa double-state via statically-indexed paA/paB (2-unrolled pair loop).
__global__ __launch_bounds__(256, 2)
void attn_kernel(const unsigned short* __restrict__ Q,
                 const unsigned short* __restrict__ Kg,
                 const unsigned short* __restrict__ Vt,
                 unsigned short* __restrict__ Ob){
  __shared__ __align__(16) unsigned short Kl[2][64*128];   // 2 x 16 KB, rows 256B, xor (row&15)<<4
  __shared__ __align__(16) unsigned short Vl[3][128*64];   // 3 x 16 KB, rows 128B, xor (row&7)<<4

  const int t = threadIdx.x;
  const int wid = t >> 6, lane = t & 63;
  const int l31 = lane & 31, hi = lane >> 5;
  const int L = blockIdx.x;
  const int bh = L & 31;
  const int z = L >> 5;
  const int qt = (z < 8) ? z : 23 - z;
  const int b = bh >> 4, h = bh & 15;
  const unsigned short* Qp = Q  + (size_t)bh * S_LEN * HD;
  const unsigned short* Kp = Kg + (size_t)bh * S_LEN * HD;
  const unsigned short* Vp = Vt + (size_t)bh * S_LEN * HD; // (d, s)
  const int q0 = qt * 128;
  const int wrow0 = q0 + wid * 32;
  const int qrow = wrow0 + l31;
  const int nt = 2 * qt + 2;              // block k-tiles (always even)
  const int ntw = (wrow0 >> 6) + 1;       // tiles this wave computes

  auto stage = [&](int tdx){
    char* kb = (char*)&Kl[tdx & 1][0];
    char* vb = (char*)&Vl[tdx % 3][0];
    const int k0 = tdx * 64;
    #pragma unroll
    for (int i = 0; i < 4; i++){ // K tile: 64 rows x 256 B
      int o = (t + i*256) * 16;
      int row = o >> 8;
      int col = (o & 255) ^ ((row & 15) << 4);
      gl_lds16((const char*)(Kp + (size_t)(k0 + row) * HD) + col, kb + o);
    }
    #pragma unroll
    for (int i = 0; i < 4; i++){ // V tile: 128 d-rows x 128 B
      int o = (t + i*256) * 16;
      int row = o >> 7;
      int col = (o & 127) ^ ((row & 7) << 4);
      gl_lds16((const char*)(Vp + (size_t)row * S_LEN + k0) + col, vb + o);
    }
  };

  // Q fragments: B[col=qrow][k=d], k = hi*8 + j within each 16-chunk
  short8 qf[8];
  #pragma unroll
  for (int dk = 0; dk < 8; dk++)
    qf[dk] = *(const short8*)(Qp + (size_t)qrow * HD + dk*16 + hi*8);

  f32x16 oacc[4];
  #pragma unroll
  for (int db = 0; db < 4; db++)
    #pragma unroll
    for (int r = 0; r < 16; r++) oacc[db][r] = 0.f;
  float mrun = -1e30f, lsum = 0.f;
  short8 paA[4], paB[4];

  auto do_pv = [&](short8 (&pprev)[4], const char* vb){
    __builtin_amdgcn_s_setprio(1);
    #pragma unroll
    for (int ks = 0; ks < 4; ks++){
      #pragma unroll
      for (int db = 0; db < 4; db++){
        int vr = db*32 + l31;
        short8 vf = *(const short8*)(vb + vr*128 + ((ks*32 + hi*16) ^ ((vr & 7) << 4)));
        oacc[db] = mfma32(vf, pprev[ks], oacc[db]);
      }
    }
    __builtin_amdgcn_s_setprio(0);
  };

  auto body = [&](int tdx, short8 (&pcur)[4], short8 (&pprev)[4]){
    if (tdx + 1 < nt) stage(tdx + 1);
    const char* Kb_ = (const char*)&Kl[tdx & 1][0];
    const bool doQK = (tdx < ntw);
    const bool doPV = (tdx >= 1) && (tdx <= ntw);

    f32x16 sacc[2];
    if (doQK){
      #pragma unroll
      for (int cb = 0; cb < 2; cb++)
        #pragma unroll
        for (int r = 0; r < 16; r++) sacc[cb][r] = 0.f;
      __builtin_amdgcn_s_setprio(1);
      #pragma unroll
      for (int dk = 0; dk < 8; dk++){
        #pragma unroll
        for (int cb = 0; cb < 2; cb++){
          int kr = cb*32 + l31;
          short8 af = *(const short8*)(Kb_ + kr*256 + ((dk*32 + hi*16) ^ ((kr & 15) << 4)));
          sacc[cb] = mfma32(af, qf[dk], sacc[cb]);
        }
      }
      __builtin_amdgcn_s_setprio(0);
    }

    if (doPV) do_pv(pprev, (const char*)&Vl[(tdx - 1) % 3][0]);

    if (doQK){
      const int k0 = tdx * 64;
      // causal mask: only the wave's diagonal tile
      if (tdx == ntw - 1){
        #pragma unroll
        for (int cb = 0; cb < 2; cb++)
          #pragma unroll
          for (int r = 0; r < 16; r++){
            int kcol = k0 + cb*32 + (r & 3) + 8*(r >> 2) + 4*hi;
            if (kcol > qrow) sacc[cb][r] = -1e30f;
          }
      }
      // online softmax (defer-max THR=8, exp2 domain)
      float mv[8];
      #pragma unroll
      for (int i = 0; i < 8; i++)
        mv[i] = fmaxf(fmaxf(sacc[0][i], sacc[0][i+8]), fmaxf(sacc[1][i], sacc[1][i+8]));
      #pragma unroll
      for (int s = 4; s > 0; s >>= 1)
        #pragma unroll
        for (int i = 0; i < 4; i++)
          if (i < s) mv[i] = fmaxf(mv[i], mv[i+s]);
      float mx = fmaxf(mv[0], __shfl_xor(mv[0], 32, 64));
      if (!__all(mx <= mrun + 8.f)){
        float mnew = fmaxf(mrun, mx);
        float alpha = exp2f(mrun - mnew);
        mrun = mnew;
        lsum *= alpha;
        #pragma unroll
        for (int db = 0; db < 4; db++)
          #pragma unroll
          for (int r = 0; r < 16; r++) oacc[db][r] *= alpha;
      }
      float ls = 0.f;
      #pragma unroll
      for (int cb = 0; cb < 2; cb++)
        #pragma unroll
        for (int r = 0; r < 16; r++){
          float p = exp2f(sacc[cb][r] - mrun);
          sacc[cb][r] = p;
          ls += p;
        }
      lsum += ls;
      // pa-build: cvt_pk + permlane32_swap (w0,w2)=(swap(B1,A1)), (w1,w3)=(swap(B2,A2))
      #pragma unroll
      for (int ks = 0; ks < 4; ks++){
        int cb = ks >> 1, bs = (ks & 1) * 8;
        unsigned B1 = cvtpk_bf16(sacc[cb][bs+0], sacc[cb][bs+1]);
        unsigned B2 = cvtpk_bf16(sacc[cb][bs+2], sacc[cb][bs+3]);
        unsigned A1 = cvtpk_bf16(sacc[cb][bs+4], sacc[cb][bs+5]);
        unsigned A2 = cvtpk_bf16(sacc[cb][bs+6], sacc[cb][bs+7]);
        asm("v_permlane32_swap_b32 %0, %1" : "+v"(B1), "+v"(A1));
        asm("v_permlane32_swap_b32 %0, %1" : "+v"(B2), "+v"(A2));
        union { unsigned u[4]; short8 v; } pk;
        pk.u[0] = B1; pk.u[1] = B2; pk.u[2] = A1; pk.u[3] = A2;
        pcur[ks] = pk.v;
      }
    }

    asm volatile("s_waitcnt vmcnt(0)" ::: "memory");
    __builtin_amdgcn_s_barrier();
  };

  stage(0);
  asm volatile("s_waitcnt vmcnt(0)" ::: "memory");
  __builtin_amdgcn_s_barrier();

  #pragma unroll 1
  for (int tt = 0; tt < nt; tt += 2){
    body(tt,     paA, paB);
    body(tt + 1, paB, paA);
  }
  // pending PV for waves with ntw == nt (nt even -> pa(nt-1) lives in paB)
  if (ntw == nt) do_pv(paB, (const char*)&Vl[(nt - 1) % 3][0]);

  // ---- epilogue: combine halves, normalize, pack, LDS transpose, coalesced store
  float lt = lsum + __shfl_xor(lsum, 32, 64);
  float inv = 1.f / lt;
  #pragma unroll
  for (int db = 0; db < 4; db++)
    #pragma unroll
    for (int r = 0; r < 16; r++) oacc[db][r] *= inv;

  __builtin_amdgcn_s_barrier();   // everyone done with K/V LDS
  char* reg_lds = (char*)&Kl[0][0] + wid * 8192;  // per-wave 32 q x 128 d x 2B
  #pragma unroll
  for (int ms = 0; ms < 8; ms++){
    int db = ms >> 1, bs = (ms & 1) * 8;
    unsigned B1 = cvtpk_bf16(oacc[db][bs+0], oacc[db][bs+1]);
    unsigned B2 = cvtpk_bf16(oacc[db][bs+2], oacc[db][bs+3]);
    unsigned A1 = cvtpk_bf16(oacc[db][bs+4], oacc[db][bs+5]);
    unsigned A2 = cvtpk_bf16(oacc[db][bs+6], oacc[db][bs+7]);
    asm("v_permlane32_swap_b32 %0, %1" : "+v"(B1), "+v"(A1));
    asm("v_permlane32_swap_b32 %0, %1" : "+v"(B2), "+v"(A2));
    union { unsigned u[4]; short8 v; } pk;
    pk.u[0] = B1; pk.u[1] = B2; pk.u[2] = A1; pk.u[3] = A2;
    int byteo = l31*256 + ((ms*32 + hi*16) ^ ((l31 & 7) << 4));
    *(short8*)(reg_lds + byteo) = pk.v;
  }
  #pragma unroll
  for (int i = 0; i < 8; i++){
    int r = (lane >> 4) + i*4;
    int c = lane & 15;
    short8 v = *(const short8*)(reg_lds + r*256 + ((c*16) ^ ((r & 7) << 4)));
    *(short8*)(Ob + ((size_t)(b * S_LEN + wrow0 + r)) * 2048 + h*128 + c*8) = v;
  }
}

// ---------------- launcher ----------------
// ws layout (bytes):
//   [0,          16777216)  xb   (4096x2048 bf16)      -- reused as Ob after QKV GEMM
//   [16777216,   41943040)  Wt   (6144x2048 bf16)
//   [41943040,   50331648)  Wot  (2048x2048 bf16)
//   [50331648,   67108864)  Qb   (b,h,s,d bf16)
//   [67108864,   83886080)  Kb
//   [83886080,  100663296)  Vt   (b,h,d,s bf16, written directly by gemm_qkv)
extern "C" void kernel_launch(void* const* d_in, const int* in_sizes, int n_in,
                              void* d_out, int out_size, void* d_ws, size_t ws_size,
                              hipStream_t stream){
  const float* x  = (const float*)d_in[0];
  // d_in[1] = mask (causal tril; hardcoded in attn_kernel)
  const float* Wq = (const float*)d_in[2];
  const float* Wk = (const float*)d_in[3];
  const float* Wv = (const float*)d_in[4];
  const float* Wo = (const float*)d_in[5];

  char* ws = (char*)d_ws;
  unsigned short* xb  = (unsigned short*)(ws);
  unsigned short* Wt  = (unsigned short*)(ws + 16777216);
  unsigned short* Wot = (unsigned short*)(ws + 41943040);
  unsigned short* Qb  = (unsigned short*)(ws + 50331648);
  unsigned short* Kb  = (unsigned short*)(ws + 67108864);
  unsigned short* Vt  = (unsigned short*)(ws + 83886080);
  unsigned short* Ob  = xb;  // alias: xb dead after gemm_qkv

  dim3 tb(32, 8);
  cast_x_kernel<<<8192, 256, 0, stream>>>(x, xb);
  transpose_cast_w4<<<dim3(64, 64, 4), tb, 0, stream>>>(Wq, Wk, Wv, Wo, Wt);

  gemm_qkv<<<dim3(32, 48), 256, 0, stream>>>(xb, Wt, Qb, Kb, Vt);

  attn_kernel<<<512, 256, 0, stream>>>(Qb, Kb, Vt, Ob);

  gemm_out<<<dim3(32, 16), 256, 0, stream>>>(Ob, Wot, (float*)d_out);
}